// Round 16
// baseline (333.526 us; speedup 1.0000x reference)
//
#include <hip/hip_runtime.h>
#include <stdint.h>

typedef unsigned short u16;
typedef unsigned int u32;
typedef __attribute__((ext_vector_type(8))) __bf16 bf16x8;
typedef __attribute__((ext_vector_type(2))) u32 u32x2;
typedef __attribute__((ext_vector_type(4))) u32 u32x4;
typedef __attribute__((ext_vector_type(4))) float f32x4;

__device__ __forceinline__ float bf2f(u16 x) { return __uint_as_float(((u32)x) << 16); }
__device__ __forceinline__ u16 f2bf(float f) {
  u32 u = __float_as_uint(f);
  u32 r = (u + 0x7fffu + ((u >> 16) & 1u)) >> 16;  // RNE
  return (u16)r;
}
// native cast -> single HW cvt instruction
__device__ __forceinline__ u16 cvbf(float f) {
  union { __bf16 b; u16 u; } x;
  x.b = (__bf16)f;
  return x.u;
}

__device__ __forceinline__ u32x2 ld8(const u16* p) { return *(const u32x2*)p; }
__device__ __forceinline__ u32x4 ld16(const u16* p) { return *(const u32x4*)p; }
__device__ __forceinline__ bf16x8 mk_frag(u32x2 lo, u32x2 hi) {
  union { bf16x8 v; u32x2 u[2]; } t;
  t.u[0] = lo; t.u[1] = hi;
  return t.v;
}

// ---------------- fragment-major LDS tile helpers (r13-verified contiguous k-map) -------------
// lane (c,g) of subtile st holds row st*16+c, cols 8g..8g+7 (16B contiguous). Same bijection
// on A and B operands -> permutation cancels in the MFMA dot product.
// LDS addr (u16): subtile*512 + g*128 + c*8.
__device__ __forceinline__ void stage_fm(u16* lds, int ch, u32x4 v) {
  int row = ch >> 2, q = ch & 3;
  *(u32x4*)&lds[(row >> 4) * 512 + q * 128 + (row & 15) * 8] = v;
}

__device__ __forceinline__ bf16x8 frag_fm(const u16* lds, int subtile, int g, int c) {
  union { bf16x8 v; u32x4 u; } t;
  t.u = ld16(&lds[subtile * 512 + g * 128 + c * 8]);
  return t.v;
}

// ---------------- XCD-chunked block swizzle (T1; r14-verified FETCH 68.7->18.2 MB) ------------
__device__ __forceinline__ void swz_bn_bm(int& bn, int& bm) {
  const u32 nx = gridDim.x, ny = gridDim.y;
  if ((ny & 7u) == 0u) {
    u32 d = blockIdx.y * nx + blockIdx.x;
    u32 xcd = d & 7u, wi = d >> 3;
    bm = (int)(xcd * (ny >> 3) + wi / nx);
    bn = (int)(wi % nx);
  } else {
    bn = blockIdx.x;
    bm = blockIdx.y;
  }
}

// ---------------- dtype probe: 1 = bf16 buffers, 0 = f32 buffers ----------------
__global__ void probe_dtype(const u32* __restrict__ x, u32* __restrict__ flag) {
  if (threadIdx.x == 0 && blockIdx.x == 0) {
    int cnt = 0;
    for (int i = 0; i < 32; ++i) {
      u32 e = (x[i] >> 7) & 0xffu;
      cnt += (e >= 96u && e <= 140u) ? 1 : 0;
    }
    *flag = (cnt == 32) ? 1u : 0u;
  }
}

// ---------------- canonicalize: src (f32 or bf16 per flag) -> bf16 ----------------
__global__ __launch_bounds__(256) void conv4(const void* __restrict__ src, u16* __restrict__ dst,
                                             const u32* __restrict__ flag, int n4) {
  const bool isbf = (*flag != 0u);
  const int stride = gridDim.x * 256;
  for (int i = blockIdx.x * 256 + threadIdx.x; i < n4; i += stride) {
    if (isbf) {
      ((u32x2*)dst)[i] = ((const u32x2*)src)[i];
    } else {
      const float* s = (const float*)src + (size_t)i * 4;
      u32x2 o;
      o.x = (u32)f2bf(s[0]) | ((u32)f2bf(s[1]) << 16);
      o.y = (u32)f2bf(s[2]) | ((u32)f2bf(s[3]) << 16);
      ((u32x2*)dst)[i] = o;
    }
  }
}

// ---------------- prep: bias table [961][16] -> [16][961] f32, PRE-SCALED by log2(e) ----------------
__global__ __launch_bounds__(256) void bias_prep(const void* __restrict__ table,
                                                 float* __restrict__ biasT,
                                                 const u32* __restrict__ flag) {
  const bool isbf = (*flag != 0u);
  int i = blockIdx.x * 256 + threadIdx.x;
  if (i < 16 * 961) {
    int h = i / 961, idx = i - h * 961;
    float v = isbf ? bf2f(((const u16*)table)[idx * 16 + h])
                   : ((const float*)table)[idx * 16 + h];
    biasT[i] = v * 1.4426950408889634f;  // log2(e): softmax runs in exp2 domain
  }
}

// ---------------- prep: transpose w_qkv [512][1536] -> bf16 [1536][512] ----------------
__global__ __launch_bounds__(256) void transpose_dt(const void* __restrict__ in,
                                                    u16* __restrict__ out,
                                                    const u32* __restrict__ flag, int R, int C) {
  __shared__ u16 t[32][33];
  const bool isbf = (*flag != 0u);
  int r0 = blockIdx.y * 32, c0 = blockIdx.x * 32;
  int rr = threadIdx.x >> 5, cc = threadIdx.x & 31;
#pragma unroll
  for (int i = 0; i < 4; ++i) {
    size_t idx = (size_t)(r0 + rr + i * 8) * C + c0 + cc;
    t[rr + i * 8][cc] = isbf ? ((const u16*)in)[idx] : f2bf(((const float*)in)[idx]);
  }
  __syncthreads();
#pragma unroll
  for (int i = 0; i < 4; ++i) out[(size_t)(c0 + rr + i * 8) * R + r0 + cc] = t[cc][rr + i * 8];
}

// ---------------- 128x128 MFMA GEMM, K=512: register-staged + XCD swizzle + T14 (r15-proven) --
template <bool BIAS>
__global__ __launch_bounds__(256) void gemm_k512(const u16* __restrict__ A,
                                                 const u16* __restrict__ BT,
                                                 const u16* __restrict__ bias,
                                                 void* __restrict__ O, int ldo, int row0g,
                                                 const u32* __restrict__ flag) {
  constexpr int K = 512;
  constexpr int NT = 16;
  __shared__ u16 As[128 * 32];
  __shared__ u16 Bs[128 * 32];
  const int tid = threadIdx.x;
  const int wave = tid >> 6, lane = tid & 63;
  const int c = lane & 15, g = lane >> 4;
  const int wm = wave >> 1, wn = wave & 1;
  int bn, bm;
  swz_bn_bm(bn, bm);

  const u16* Ab = A + (size_t)bm * 128 * K;
  const u16* Bb = BT + (size_t)bn * 128 * K;

  const int row0 = tid >> 2, q0 = tid & 3;
  const u16* Asrc0 = Ab + (size_t)row0 * K + q0 * 8;
  const u16* Bsrc0 = Bb + (size_t)row0 * K + q0 * 8;
  const u16* Asrc1 = Asrc0 + (size_t)64 * K;
  const u16* Bsrc1 = Bsrc0 + (size_t)64 * K;

  f32x4 acc[4][4] = {};

  u32x4 a0 = ld16(Asrc0), b0 = ld16(Bsrc0), a1 = ld16(Asrc1), b1 = ld16(Bsrc1);

#pragma unroll
  for (int t = 0; t < NT; ++t) {
    if (t > 0) {
      asm volatile("s_waitcnt lgkmcnt(0)" ::: "memory");
      __builtin_amdgcn_s_barrier();
      __builtin_amdgcn_sched_barrier(0);
    }
    stage_fm(As, tid, a0);
    stage_fm(Bs, tid, b0);
    stage_fm(As, tid + 256, a1);
    stage_fm(Bs, tid + 256, b1);
    if (t + 1 < NT) {  // T14: issue next-tile loads; they fly across barrier + MFMAs
      const int k0 = (t + 1) * 32;
      a0 = ld16(Asrc0 + k0);
      b0 = ld16(Bsrc0 + k0);
      a1 = ld16(Asrc1 + k0);
      b1 = ld16(Bsrc1 + k0);
    }
    asm volatile("s_waitcnt lgkmcnt(0)" ::: "memory");
    __builtin_amdgcn_s_barrier();
    __builtin_amdgcn_sched_barrier(0);

    bf16x8 af[4], bfr[4];
#pragma unroll
    for (int i = 0; i < 4; ++i) {
      af[i] = frag_fm(As, wm * 4 + i, g, c);
      bfr[i] = frag_fm(Bs, wn * 4 + i, g, c);
    }
#pragma unroll
    for (int i = 0; i < 4; ++i)
#pragma unroll
      for (int j = 0; j < 4; ++j)
        acc[i][j] = __builtin_amdgcn_mfma_f32_16x16x32_bf16(af[i], bfr[j], acc[i][j], 0, 0, 0);
  }

  const bool isbf = BIAS ? (*flag != 0u) : true;
#pragma unroll
  for (int i = 0; i < 4; ++i)
#pragma unroll
    for (int j = 0; j < 4; ++j) {
      int jg = bn * 128 + wn * 64 + j * 16 + c;
      float bv = BIAS ? bf2f(bias[jg]) : 0.0f;
#pragma unroll
      for (int r = 0; r < 4; ++r) {
        int mg = bm * 128 + wm * 64 + i * 16 + 4 * g + r;
        float v = acc[i][j][r] + bv;
        size_t off = (size_t)(row0g + mg) * ldo + jg;
        if (BIAS) {
          if (isbf) ((u16*)O)[off] = f2bf(v);
          else ((float*)O)[off] = v;
        } else {
          ((u16*)O)[off] = f2bf(v);
        }
      }
    }
}

// ---------------- fused attention: block per (b,h,half); K from L2, LDS = V + bias only -------
// Occupancy play: LDS 20480 B (8 blocks/CU) + launch_bounds(256,8) pinning VGPR <= 64
// (2x resident waves vs r15). K fragments are 16B-contiguous in global under the k-map ->
// read straight from L2 (no staging); Q loaded per-rg; s[8] phase-split keeps live set small.
__global__ __launch_bounds__(256, 8) void attn_kernel(const u16* __restrict__ qkv,
                                                      const float* __restrict__ biasT,
                                                      u16* __restrict__ Out) {
  __shared__ u16 smem[10240];  // [0,8192) Vt [32][256] swizzled; f32 bias @ u16 8192 (961)
  float* biasS = (float*)&smem[8192];

  const int tid = threadIdx.x;
  const int wave = tid >> 6, lane = tid & 63;
  const int c = lane & 15, g = lane >> 4;
  const int half = blockIdx.x & 1;
  const int h = (blockIdx.x >> 1) & 15;
  const int b = blockIdx.x >> 5;

  const u16* xb = qkv + (size_t)b * 256 * 1536;

  // stage V transposed + swizzled: element (n,d) -> Vt[d][n ^ 8*(d&7)]
#pragma unroll
  for (int i = 0; i < 16; ++i) {
    int e2 = tid + i * 256;
    int n = e2 >> 4, d = (e2 & 15) * 2;
    u32 val = *(const u32*)(xb + (size_t)n * 1536 + 1024 + h * 32 + d);
    smem[d * 256 + (n ^ (8 * (d & 7)))] = (u16)(val & 0xffffu);
    smem[(d + 1) * 256 + (n ^ (8 * ((d + 1) & 7)))] = (u16)(val >> 16);
  }
  // bias: coalesced f32 row for this head (already *log2e)
  for (int i = tid; i < 961; i += 256) biasS[i] = biasT[h * 961 + i];
  __syncthreads();  // only barrier

  const u16* Vt = &smem[0];
  const int va = 8 * (c & 7);
  const float scale2 = 0.25503484f;  // log2(e) / sqrt(32)
  const float* bp0 = biasS + wave * 31 + c + 12 - 4 * g;
  // K fragment column base: row c, this lane's 8 dims; subtile stride = 16*1536 elems
  const u16* kcol = xb + (size_t)c * 1536 + 512 + h * 32 + 8 * g;

  for (int rg = 0; rg < 2; ++rg) {
    const int rgg = half * 2 + rg;
    union { bf16x8 v; u32x4 u; } qt;
    qt.u = ld16(xb + (size_t)(rgg * 64 + wave * 16 + c) * 1536 + h * 32 + 8 * g);
    bf16x8 qf = qt.v;

    f32x4 o0 = {0.f, 0.f, 0.f, 0.f}, o1 = {0.f, 0.f, 0.f, 0.f};
    float smA = 0.f, smB = 0.f;

#pragma unroll
    for (int ph = 0; ph < 2; ++ph) {
      // QK^T for 8 fragments, K straight from global/L2 (16B contiguous per lane)
      f32x4 s[8];
      const u16* kp = kcol + (size_t)(ph * 8) * 24576;
#pragma unroll
      for (int f = 0; f < 8; ++f) {
        union { bf16x8 v; u32x4 u; } kt;
        kt.u = ld16(kp);
        kp += 24576;
        f32x4 z = {0.f, 0.f, 0.f, 0.f};
        s[f] = __builtin_amdgcn_mfma_f32_16x16x32_bf16(kt.v, qf, z, 0, 0, 0);
      }

      // P = exp2(s*scale2 + bias), unnormalized; two running partial sums
#pragma unroll
      for (int f = 0; f < 8; ++f) {
        const int fg = ph * 8 + f;
#pragma unroll
        for (int j = 0; j < 4; ++j) {
          float bv = bp0[(rgg * 4 - fg + 15) * 31 + 3 - j];
          s[f][j] = __builtin_amdgcn_exp2f(s[f][j] * scale2 + bv);
        }
        if (f & 1) smB += (s[f][0] + s[f][1]) + (s[f][2] + s[f][3]);
        else smA += (s[f][0] + s[f][1]) + (s[f][2] + s[f][3]);
      }

      // PV for this phase's 4 k-blocks (frees s before next phase)
#pragma unroll
      for (int q = 0; q < 4; ++q) {
        bf16x8 pf;
        pf[0] = (__bf16)s[2 * q][0]; pf[1] = (__bf16)s[2 * q][1];
        pf[2] = (__bf16)s[2 * q][2]; pf[3] = (__bf16)s[2 * q][3];
        pf[4] = (__bf16)s[2 * q + 1][0]; pf[5] = (__bf16)s[2 * q + 1][1];
        pf[6] = (__bf16)s[2 * q + 1][2]; pf[7] = (__bf16)s[2 * q + 1][3];
        const int kg = (ph * 4 + q) * 32;
        bf16x8 v0 = mk_frag(ld8(&Vt[c * 256 + ((kg + 4 * g) ^ va)]),
                            ld8(&Vt[c * 256 + ((kg + 16 + 4 * g) ^ va)]));
        bf16x8 v1 = mk_frag(ld8(&Vt[(16 + c) * 256 + ((kg + 4 * g) ^ va)]),
                            ld8(&Vt[(16 + c) * 256 + ((kg + 16 + 4 * g) ^ va)]));
        o0 = __builtin_amdgcn_mfma_f32_16x16x32_bf16(pf, v0, o0, 0, 0, 0);
        o1 = __builtin_amdgcn_mfma_f32_16x16x32_bf16(pf, v1, o1, 0, 0, 0);
      }
    }

    float smm = smA + smB;
    smm += __shfl_xor(smm, 16, 64);
    smm += __shfl_xor(smm, 32, 64);
    const float invc = __builtin_amdgcn_rcpf(smm);

    const int nb = rgg * 64 + wave * 16 + 4 * g;
#pragma unroll
    for (int j = 0; j < 4; ++j) {
      int n = nb + j;
      size_t off = ((size_t)b * 256 + n) * 512 + h * 32;
      Out[off + c] = cvbf(o0[j] * invc);
      Out[off + 16 + c] = cvbf(o1[j] * invc);
    }
  }
}

extern "C" void kernel_launch(void* const* d_in, const int* in_sizes, int n_in, void* d_out,
                              int out_size, void* d_ws, size_t ws_size, hipStream_t stream) {
  (void)in_sizes; (void)n_in; (void)out_size;
  const void* x = d_in[0];
  const void* w_qkv = d_in[1];
  const void* table = d_in[2];
  const void* w_out = d_in[3];
  const void* b_out = d_in[4];

  // Workspace layout (bytes):
  //   0        flag (u32, 256B reserved)
  //   256      xc     bf16 [16384][512]   16,777,216
  //   16777472 wqkvT  bf16 [1536][512]     1,572,864
  //   18350336 biasT  f32  [16][961]          61,504
  //   18411840 woC    bf16 [512][512]        524,288
  //   18936128 bC     bf16 [512]               1,024
  //   18937344 qkv chunk bf16 [CB*256][1536] + att chunk bf16 [CB*256][512]
  char* ws = (char*)d_ws;
  u32* flag = (u32*)ws;
  u16* xc = (u16*)(ws + 256);
  u16* wqkvT = (u16*)(ws + 16777472);
  float* biasT = (float*)(ws + 18350336);
  u16* woC = (u16*)(ws + 18411840);
  u16* bC = (u16*)(ws + 18936128);
  const size_t DYN = 18937344;
  int CB = 64;
  while (CB > 1 && DYN + (size_t)CB * 1048576 > ws_size) CB >>= 1;
  u16* qkv = (u16*)(ws + DYN);
  u16* att = (u16*)(ws + DYN + (size_t)CB * 786432);

  dim3 blk(256);
  probe_dtype<<<dim3(1), dim3(64), 0, stream>>>((const u32*)x, flag);
  conv4<<<dim3(2048), blk, 0, stream>>>(x, xc, flag, 2097152);
  conv4<<<dim3(256), blk, 0, stream>>>(w_out, woC, flag, 65536);
  conv4<<<dim3(1), blk, 0, stream>>>(b_out, bC, flag, 128);
  bias_prep<<<dim3(61), blk, 0, stream>>>(table, biasT, flag);
  transpose_dt<<<dim3(48, 16), blk, 0, stream>>>(w_qkv, wqkvT, flag, 512, 1536);

  for (int s0 = 0; s0 < 64; s0 += CB) {
    const u16* xcc = xc + (size_t)s0 * 256 * 512;
    gemm_k512<false><<<dim3(12, CB * 2), blk, 0, stream>>>(xcc, wqkvT, nullptr, qkv, 1536, 0,
                                                           flag);
    attn_kernel<<<dim3(CB * 32), blk, 0, stream>>>(qkv, biasT, att);
    gemm_k512<true><<<dim3(4, CB * 2), blk, 0, stream>>>(att, woC, bC, d_out, 512, s0 * 256,
                                                         flag);
  }
}

// Round 17
// 131.068 us; speedup vs baseline: 2.5447x; 2.5447x over previous
//
#include <hip/hip_runtime.h>
#include <stdint.h>

typedef unsigned short u16;
typedef unsigned int u32;
typedef __attribute__((ext_vector_type(8))) __bf16 bf16x8;
typedef __attribute__((ext_vector_type(2))) u32 u32x2;
typedef __attribute__((ext_vector_type(4))) u32 u32x4;
typedef __attribute__((ext_vector_type(4))) float f32x4;

__device__ __forceinline__ float bf2f(u16 x) { return __uint_as_float(((u32)x) << 16); }
__device__ __forceinline__ u16 f2bf(float f) {
  u32 u = __float_as_uint(f);
  u32 r = (u + 0x7fffu + ((u >> 16) & 1u)) >> 16;  // RNE
  return (u16)r;
}
// native cast -> single HW cvt instruction
__device__ __forceinline__ u16 cvbf(float f) {
  union { __bf16 b; u16 u; } x;
  x.b = (__bf16)f;
  return x.u;
}

__device__ __forceinline__ u32x2 ld8(const u16* p) { return *(const u32x2*)p; }
__device__ __forceinline__ u32x4 ld16(const u16* p) { return *(const u32x4*)p; }
__device__ __forceinline__ bf16x8 mk_frag(u32x2 lo, u32x2 hi) {
  union { bf16x8 v; u32x2 u[2]; } t;
  t.u[0] = lo; t.u[1] = hi;
  return t.v;
}

// ---------------- fragment-major LDS tile helpers (r13-verified contiguous k-map) -------------
// lane (c,g) of subtile st holds row st*16+c, cols 8g..8g+7 (16B contiguous). Same bijection
// on A and B operands -> permutation cancels in the MFMA dot product.
// LDS addr (u16): subtile*512 + g*128 + c*8.
__device__ __forceinline__ void stage_fm(u16* lds, int ch, u32x4 v) {
  int row = ch >> 2, q = ch & 3;
  *(u32x4*)&lds[(row >> 4) * 512 + q * 128 + (row & 15) * 8] = v;
}

__device__ __forceinline__ bf16x8 frag_fm(const u16* lds, int subtile, int g, int c) {
  union { bf16x8 v; u32x4 u; } t;
  t.u = ld16(&lds[subtile * 512 + g * 128 + c * 8]);
  return t.v;
}

// ---------------- XCD-chunked block swizzle (T1; r14-verified FETCH 68.7->18.2 MB) ------------
__device__ __forceinline__ void swz_bn_bm(int& bn, int& bm) {
  const u32 nx = gridDim.x, ny = gridDim.y;
  if ((ny & 7u) == 0u) {
    u32 d = blockIdx.y * nx + blockIdx.x;
    u32 xcd = d & 7u, wi = d >> 3;
    bm = (int)(xcd * (ny >> 3) + wi / nx);
    bn = (int)(wi % nx);
  } else {
    bn = blockIdx.x;
    bm = blockIdx.y;
  }
}

// ---------------- dtype probe: 1 = bf16 buffers, 0 = f32 buffers ----------------
__global__ void probe_dtype(const u32* __restrict__ x, u32* __restrict__ flag) {
  if (threadIdx.x == 0 && blockIdx.x == 0) {
    int cnt = 0;
    for (int i = 0; i < 32; ++i) {
      u32 e = (x[i] >> 7) & 0xffu;
      cnt += (e >= 96u && e <= 140u) ? 1 : 0;
    }
    *flag = (cnt == 32) ? 1u : 0u;
  }
}

// ---------------- canonicalize: src (f32 or bf16 per flag) -> bf16 ----------------
__global__ __launch_bounds__(256) void conv4(const void* __restrict__ src, u16* __restrict__ dst,
                                             const u32* __restrict__ flag, int n4) {
  const bool isbf = (*flag != 0u);
  const int stride = gridDim.x * 256;
  for (int i = blockIdx.x * 256 + threadIdx.x; i < n4; i += stride) {
    if (isbf) {
      ((u32x2*)dst)[i] = ((const u32x2*)src)[i];
    } else {
      const float* s = (const float*)src + (size_t)i * 4;
      u32x2 o;
      o.x = (u32)f2bf(s[0]) | ((u32)f2bf(s[1]) << 16);
      o.y = (u32)f2bf(s[2]) | ((u32)f2bf(s[3]) << 16);
      ((u32x2*)dst)[i] = o;
    }
  }
}

// ---------------- prep: bias table [961][16] -> [16][961] f32, PRE-SCALED by log2(e) ----------------
__global__ __launch_bounds__(256) void bias_prep(const void* __restrict__ table,
                                                 float* __restrict__ biasT,
                                                 const u32* __restrict__ flag) {
  const bool isbf = (*flag != 0u);
  int i = blockIdx.x * 256 + threadIdx.x;
  if (i < 16 * 961) {
    int h = i / 961, idx = i - h * 961;
    float v = isbf ? bf2f(((const u16*)table)[idx * 16 + h])
                   : ((const float*)table)[idx * 16 + h];
    biasT[i] = v * 1.4426950408889634f;  // log2(e): softmax runs in exp2 domain
  }
}

// ---------------- prep: transpose w_qkv [512][1536] -> bf16 [1536][512] ----------------
__global__ __launch_bounds__(256) void transpose_dt(const void* __restrict__ in,
                                                    u16* __restrict__ out,
                                                    const u32* __restrict__ flag, int R, int C) {
  __shared__ u16 t[32][33];
  const bool isbf = (*flag != 0u);
  int r0 = blockIdx.y * 32, c0 = blockIdx.x * 32;
  int rr = threadIdx.x >> 5, cc = threadIdx.x & 31;
#pragma unroll
  for (int i = 0; i < 4; ++i) {
    size_t idx = (size_t)(r0 + rr + i * 8) * C + c0 + cc;
    t[rr + i * 8][cc] = isbf ? ((const u16*)in)[idx] : f2bf(((const float*)in)[idx]);
  }
  __syncthreads();
#pragma unroll
  for (int i = 0; i < 4; ++i) out[(size_t)(c0 + rr + i * 8) * R + r0 + cc] = t[cc][rr + i * 8];
}

// ---------------- 128x128 MFMA GEMM, K=512: register-staged + XCD swizzle + T14 (r15-proven) --
template <bool BIAS>
__global__ __launch_bounds__(256) void gemm_k512(const u16* __restrict__ A,
                                                 const u16* __restrict__ BT,
                                                 const u16* __restrict__ bias,
                                                 void* __restrict__ O, int ldo, int row0g,
                                                 const u32* __restrict__ flag) {
  constexpr int K = 512;
  constexpr int NT = 16;
  __shared__ u16 As[128 * 32];
  __shared__ u16 Bs[128 * 32];
  const int tid = threadIdx.x;
  const int wave = tid >> 6, lane = tid & 63;
  const int c = lane & 15, g = lane >> 4;
  const int wm = wave >> 1, wn = wave & 1;
  int bn, bm;
  swz_bn_bm(bn, bm);

  const u16* Ab = A + (size_t)bm * 128 * K;
  const u16* Bb = BT + (size_t)bn * 128 * K;

  const int row0 = tid >> 2, q0 = tid & 3;
  const u16* Asrc0 = Ab + (size_t)row0 * K + q0 * 8;
  const u16* Bsrc0 = Bb + (size_t)row0 * K + q0 * 8;
  const u16* Asrc1 = Asrc0 + (size_t)64 * K;
  const u16* Bsrc1 = Bsrc0 + (size_t)64 * K;

  f32x4 acc[4][4] = {};

  u32x4 a0 = ld16(Asrc0), b0 = ld16(Bsrc0), a1 = ld16(Asrc1), b1 = ld16(Bsrc1);

#pragma unroll
  for (int t = 0; t < NT; ++t) {
    if (t > 0) {
      asm volatile("s_waitcnt lgkmcnt(0)" ::: "memory");
      __builtin_amdgcn_s_barrier();
      __builtin_amdgcn_sched_barrier(0);
    }
    stage_fm(As, tid, a0);
    stage_fm(Bs, tid, b0);
    stage_fm(As, tid + 256, a1);
    stage_fm(Bs, tid + 256, b1);
    if (t + 1 < NT) {  // T14: issue next-tile loads; they fly across barrier + MFMAs
      const int k0 = (t + 1) * 32;
      a0 = ld16(Asrc0 + k0);
      b0 = ld16(Bsrc0 + k0);
      a1 = ld16(Asrc1 + k0);
      b1 = ld16(Bsrc1 + k0);
    }
    asm volatile("s_waitcnt lgkmcnt(0)" ::: "memory");
    __builtin_amdgcn_s_barrier();
    __builtin_amdgcn_sched_barrier(0);

    bf16x8 af[4], bfr[4];
#pragma unroll
    for (int i = 0; i < 4; ++i) {
      af[i] = frag_fm(As, wm * 4 + i, g, c);
      bfr[i] = frag_fm(Bs, wn * 4 + i, g, c);
    }
#pragma unroll
    for (int i = 0; i < 4; ++i)
#pragma unroll
      for (int j = 0; j < 4; ++j)
        acc[i][j] = __builtin_amdgcn_mfma_f32_16x16x32_bf16(af[i], bfr[j], acc[i][j], 0, 0, 0);
  }

  const bool isbf = BIAS ? (*flag != 0u) : true;
#pragma unroll
  for (int i = 0; i < 4; ++i)
#pragma unroll
    for (int j = 0; j < 4; ++j) {
      int jg = bn * 128 + wn * 64 + j * 16 + c;
      float bv = BIAS ? bf2f(bias[jg]) : 0.0f;
#pragma unroll
      for (int r = 0; r < 4; ++r) {
        int mg = bm * 128 + wm * 64 + i * 16 + 4 * g + r;
        float v = acc[i][j][r] + bv;
        size_t off = (size_t)(row0g + mg) * ldo + jg;
        if (BIAS) {
          if (isbf) ((u16*)O)[off] = f2bf(v);
          else ((float*)O)[off] = v;
        } else {
          ((u16*)O)[off] = f2bf(v);
        }
      }
    }
}

// ---------------- fused attention: block per (b,h,half); K from L2, LDS = V + bias only -------
// r16 retry WITHOUT the launch_bounds waves pin (r16: pin->VGPR 32->457MB scratch spill).
// Natural VGPR ~72-84 -> ~6 waves/SIMD; LDS 20480 allows 8 blocks/CU -> occupancy bound by
// VGPR at ~24 waves/CU, 1.5x r15's 16, zero spills.
__global__ __launch_bounds__(256) void attn_kernel(const u16* __restrict__ qkv,
                                                   const float* __restrict__ biasT,
                                                   u16* __restrict__ Out) {
  __shared__ u16 smem[10240];  // [0,8192) Vt [32][256] swizzled; f32 bias @ u16 8192 (961)
  float* biasS = (float*)&smem[8192];

  const int tid = threadIdx.x;
  const int wave = tid >> 6, lane = tid & 63;
  const int c = lane & 15, g = lane >> 4;
  const int half = blockIdx.x & 1;
  const int h = (blockIdx.x >> 1) & 15;
  const int b = blockIdx.x >> 5;

  const u16* xb = qkv + (size_t)b * 256 * 1536;

  // stage V transposed + swizzled: element (n,d) -> Vt[d][n ^ 8*(d&7)]
#pragma unroll
  for (int i = 0; i < 16; ++i) {
    int e2 = tid + i * 256;
    int n = e2 >> 4, d = (e2 & 15) * 2;
    u32 val = *(const u32*)(xb + (size_t)n * 1536 + 1024 + h * 32 + d);
    smem[d * 256 + (n ^ (8 * (d & 7)))] = (u16)(val & 0xffffu);
    smem[(d + 1) * 256 + (n ^ (8 * ((d + 1) & 7)))] = (u16)(val >> 16);
  }
  // bias: coalesced f32 row for this head (already *log2e)
  for (int i = tid; i < 961; i += 256) biasS[i] = biasT[h * 961 + i];
  __syncthreads();  // only barrier

  const u16* Vt = &smem[0];
  const int va = 8 * (c & 7);
  const float scale2 = 0.25503484f;  // log2(e) / sqrt(32)
  const float* bp0 = biasS + wave * 31 + c + 12 - 4 * g;
  // K fragment column base: row c, this lane's 8 dims; subtile stride = 16*1536 elems
  const u16* kcol = xb + (size_t)c * 1536 + 512 + h * 32 + 8 * g;

  for (int rg = 0; rg < 2; ++rg) {
    const int rgg = half * 2 + rg;
    union { bf16x8 v; u32x4 u; } qt;
    qt.u = ld16(xb + (size_t)(rgg * 64 + wave * 16 + c) * 1536 + h * 32 + 8 * g);
    bf16x8 qf = qt.v;

    f32x4 o0 = {0.f, 0.f, 0.f, 0.f}, o1 = {0.f, 0.f, 0.f, 0.f};
    float smA = 0.f, smB = 0.f;

#pragma unroll
    for (int ph = 0; ph < 2; ++ph) {
      // QK^T for 8 fragments, K straight from global/L2 (16B contiguous per lane)
      f32x4 s[8];
      const u16* kp = kcol + (size_t)(ph * 8) * 24576;
#pragma unroll
      for (int f = 0; f < 8; ++f) {
        union { bf16x8 v; u32x4 u; } kt;
        kt.u = ld16(kp);
        kp += 24576;
        f32x4 z = {0.f, 0.f, 0.f, 0.f};
        s[f] = __builtin_amdgcn_mfma_f32_16x16x32_bf16(kt.v, qf, z, 0, 0, 0);
      }

      // P = exp2(s*scale2 + bias), unnormalized; two running partial sums
#pragma unroll
      for (int f = 0; f < 8; ++f) {
        const int fg = ph * 8 + f;
#pragma unroll
        for (int j = 0; j < 4; ++j) {
          float bv = bp0[(rgg * 4 - fg + 15) * 31 + 3 - j];
          s[f][j] = __builtin_amdgcn_exp2f(s[f][j] * scale2 + bv);
        }
        if (f & 1) smB += (s[f][0] + s[f][1]) + (s[f][2] + s[f][3]);
        else smA += (s[f][0] + s[f][1]) + (s[f][2] + s[f][3]);
      }

      // PV for this phase's 4 k-blocks (frees s before next phase)
#pragma unroll
      for (int q = 0; q < 4; ++q) {
        bf16x8 pf;
        pf[0] = (__bf16)s[2 * q][0]; pf[1] = (__bf16)s[2 * q][1];
        pf[2] = (__bf16)s[2 * q][2]; pf[3] = (__bf16)s[2 * q][3];
        pf[4] = (__bf16)s[2 * q + 1][0]; pf[5] = (__bf16)s[2 * q + 1][1];
        pf[6] = (__bf16)s[2 * q + 1][2]; pf[7] = (__bf16)s[2 * q + 1][3];
        const int kg = (ph * 4 + q) * 32;
        bf16x8 v0 = mk_frag(ld8(&Vt[c * 256 + ((kg + 4 * g) ^ va)]),
                            ld8(&Vt[c * 256 + ((kg + 16 + 4 * g) ^ va)]));
        bf16x8 v1 = mk_frag(ld8(&Vt[(16 + c) * 256 + ((kg + 4 * g) ^ va)]),
                            ld8(&Vt[(16 + c) * 256 + ((kg + 16 + 4 * g) ^ va)]));
        o0 = __builtin_amdgcn_mfma_f32_16x16x32_bf16(pf, v0, o0, 0, 0, 0);
        o1 = __builtin_amdgcn_mfma_f32_16x16x32_bf16(pf, v1, o1, 0, 0, 0);
      }
    }

    float smm = smA + smB;
    smm += __shfl_xor(smm, 16, 64);
    smm += __shfl_xor(smm, 32, 64);
    const float invc = __builtin_amdgcn_rcpf(smm);

    const int nb = rgg * 64 + wave * 16 + 4 * g;
#pragma unroll
    for (int j = 0; j < 4; ++j) {
      int n = nb + j;
      size_t off = ((size_t)b * 256 + n) * 512 + h * 32;
      Out[off + c] = cvbf(o0[j] * invc);
      Out[off + 16 + c] = cvbf(o1[j] * invc);
    }
  }
}

extern "C" void kernel_launch(void* const* d_in, const int* in_sizes, int n_in, void* d_out,
                              int out_size, void* d_ws, size_t ws_size, hipStream_t stream) {
  (void)in_sizes; (void)n_in; (void)out_size;
  const void* x = d_in[0];
  const void* w_qkv = d_in[1];
  const void* table = d_in[2];
  const void* w_out = d_in[3];
  const void* b_out = d_in[4];

  // Workspace layout (bytes):
  //   0        flag (u32, 256B reserved)
  //   256      xc     bf16 [16384][512]   16,777,216
  //   16777472 wqkvT  bf16 [1536][512]     1,572,864
  //   18350336 biasT  f32  [16][961]          61,504
  //   18411840 woC    bf16 [512][512]        524,288
  //   18936128 bC     bf16 [512]               1,024
  //   18937344 qkv chunk bf16 [CB*256][1536] + att chunk bf16 [CB*256][512]
  char* ws = (char*)d_ws;
  u32* flag = (u32*)ws;
  u16* xc = (u16*)(ws + 256);
  u16* wqkvT = (u16*)(ws + 16777472);
  float* biasT = (float*)(ws + 18350336);
  u16* woC = (u16*)(ws + 18411840);
  u16* bC = (u16*)(ws + 18936128);
  const size_t DYN = 18937344;
  int CB = 64;
  while (CB > 1 && DYN + (size_t)CB * 1048576 > ws_size) CB >>= 1;
  u16* qkv = (u16*)(ws + DYN);
  u16* att = (u16*)(ws + DYN + (size_t)CB * 786432);

  dim3 blk(256);
  probe_dtype<<<dim3(1), dim3(64), 0, stream>>>((const u32*)x, flag);
  conv4<<<dim3(2048), blk, 0, stream>>>(x, xc, flag, 2097152);
  conv4<<<dim3(256), blk, 0, stream>>>(w_out, woC, flag, 65536);
  conv4<<<dim3(1), blk, 0, stream>>>(b_out, bC, flag, 128);
  bias_prep<<<dim3(61), blk, 0, stream>>>(table, biasT, flag);
  transpose_dt<<<dim3(48, 16), blk, 0, stream>>>(w_qkv, wqkvT, flag, 512, 1536);

  for (int s0 = 0; s0 < 64; s0 += CB) {
    const u16* xcc = xc + (size_t)s0 * 256 * 512;
    gemm_k512<false><<<dim3(12, CB * 2), blk, 0, stream>>>(xcc, wqkvT, nullptr, qkv, 1536, 0,
                                                           flag);
    attn_kernel<<<dim3(CB * 32), blk, 0, stream>>>(qkv, biasT, att);
    gemm_k512<true><<<dim3(4, CB * 2), blk, 0, stream>>>(att, woC, bC, d_out, 512, s0 * 256,
                                                         flag);
  }
}

// Round 18
// 124.627 us; speedup vs baseline: 2.6762x; 1.0517x over previous
//
#include <hip/hip_runtime.h>
#include <stdint.h>

typedef unsigned short u16;
typedef unsigned int u32;
typedef __attribute__((ext_vector_type(8))) __bf16 bf16x8;
typedef __attribute__((ext_vector_type(2))) u32 u32x2;
typedef __attribute__((ext_vector_type(4))) u32 u32x4;
typedef __attribute__((ext_vector_type(4))) float f32x4;

__device__ __forceinline__ float bf2f(u16 x) { return __uint_as_float(((u32)x) << 16); }
__device__ __forceinline__ u16 f2bf(float f) {
  u32 u = __float_as_uint(f);
  u32 r = (u + 0x7fffu + ((u >> 16) & 1u)) >> 16;  // RNE
  return (u16)r;
}
// native cast -> single HW cvt instruction
__device__ __forceinline__ u16 cvbf(float f) {
  union { __bf16 b; u16 u; } x;
  x.b = (__bf16)f;
  return x.u;
}

__device__ __forceinline__ u32x2 ld8(const u16* p) { return *(const u32x2*)p; }
__device__ __forceinline__ u32x4 ld16(const u16* p) { return *(const u32x4*)p; }
__device__ __forceinline__ u32x4 ld16f(const float* p) { return *(const u32x4*)p; }
__device__ __forceinline__ bf16x8 mk_frag(u32x2 lo, u32x2 hi) {
  union { bf16x8 v; u32x2 u[2]; } t;
  t.u[0] = lo; t.u[1] = hi;
  return t.v;
}
// 8 f32 (two u32x4 views) -> 8 bf16 chunk; compiler emits v_cvt_pk_bf16_f32 pairs
__device__ __forceinline__ u32x4 cvt8(u32x4 lo, u32x4 hi) {
  union { u32x4 u; float f[4]; } a, b;
  a.u = lo; b.u = hi;
  union { u32x4 u; __bf16 h[8]; } o;
#pragma unroll
  for (int i = 0; i < 4; ++i) {
    o.h[i] = (__bf16)a.f[i];
    o.h[4 + i] = (__bf16)b.f[i];
  }
  return o.u;
}

// ---------------- fragment-major LDS tile helpers (r13-verified contiguous k-map) -------------
__device__ __forceinline__ void stage_fm(u16* lds, int ch, u32x4 v) {
  int row = ch >> 2, q = ch & 3;
  *(u32x4*)&lds[(row >> 4) * 512 + q * 128 + (row & 15) * 8] = v;
}

__device__ __forceinline__ bf16x8 frag_fm(const u16* lds, int subtile, int g, int c) {
  union { bf16x8 v; u32x4 u; } t;
  t.u = ld16(&lds[subtile * 512 + g * 128 + c * 8]);
  return t.v;
}

// ---------------- XCD-chunked block swizzle (T1; r14-verified FETCH 68.7->18.2 MB) ------------
__device__ __forceinline__ void swz_bn_bm(int& bn, int& bm) {
  const u32 nx = gridDim.x, ny = gridDim.y;
  if ((ny & 7u) == 0u) {
    u32 d = blockIdx.y * nx + blockIdx.x;
    u32 xcd = d & 7u, wi = d >> 3;
    bm = (int)(xcd * (ny >> 3) + wi / nx);
    bn = (int)(wi % nx);
  } else {
    bn = blockIdx.x;
    bm = blockIdx.y;
  }
}

// ---------------- dtype probe: 1 = bf16 buffers, 0 = f32 buffers ----------------
__global__ void probe_dtype(const u32* __restrict__ x, u32* __restrict__ flag) {
  if (threadIdx.x == 0 && blockIdx.x == 0) {
    int cnt = 0;
    for (int i = 0; i < 32; ++i) {
      u32 e = (x[i] >> 7) & 0xffu;
      cnt += (e >= 96u && e <= 140u) ? 1 : 0;
    }
    *flag = (cnt == 32) ? 1u : 0u;
  }
}

// ---------------- canonicalize: src (f32 or bf16 per flag) -> bf16 ----------------
__global__ __launch_bounds__(256) void conv4(const void* __restrict__ src, u16* __restrict__ dst,
                                             const u32* __restrict__ flag, int n4) {
  const bool isbf = (*flag != 0u);
  const int stride = gridDim.x * 256;
  for (int i = blockIdx.x * 256 + threadIdx.x; i < n4; i += stride) {
    if (isbf) {
      ((u32x2*)dst)[i] = ((const u32x2*)src)[i];
    } else {
      const float* s = (const float*)src + (size_t)i * 4;
      u32x2 o;
      o.x = (u32)f2bf(s[0]) | ((u32)f2bf(s[1]) << 16);
      o.y = (u32)f2bf(s[2]) | ((u32)f2bf(s[3]) << 16);
      ((u32x2*)dst)[i] = o;
    }
  }
}

// ---------------- prep: bias table [961][16] -> [16][961] f32, PRE-SCALED by log2(e) ----------------
__global__ __launch_bounds__(256) void bias_prep(const void* __restrict__ table,
                                                 float* __restrict__ biasT,
                                                 const u32* __restrict__ flag) {
  const bool isbf = (*flag != 0u);
  int i = blockIdx.x * 256 + threadIdx.x;
  if (i < 16 * 961) {
    int h = i / 961, idx = i - h * 961;
    float v = isbf ? bf2f(((const u16*)table)[idx * 16 + h])
                   : ((const float*)table)[idx * 16 + h];
    biasT[i] = v * 1.4426950408889634f;  // log2(e): softmax runs in exp2 domain
  }
}

// ---------------- prep: transpose w_qkv [512][1536] -> bf16 [1536][512] ----------------
__global__ __launch_bounds__(256) void transpose_dt(const void* __restrict__ in,
                                                    u16* __restrict__ out,
                                                    const u32* __restrict__ flag, int R, int C) {
  __shared__ u16 t[32][33];
  const bool isbf = (*flag != 0u);
  int r0 = blockIdx.y * 32, c0 = blockIdx.x * 32;
  int rr = threadIdx.x >> 5, cc = threadIdx.x & 31;
#pragma unroll
  for (int i = 0; i < 4; ++i) {
    size_t idx = (size_t)(r0 + rr + i * 8) * C + c0 + cc;
    t[rr + i * 8][cc] = isbf ? ((const u16*)in)[idx] : f2bf(((const float*)in)[idx]);
  }
  __syncthreads();
#pragma unroll
  for (int i = 0; i < 4; ++i) out[(size_t)(c0 + rr + i * 8) * R + r0 + cc] = t[cc][rr + i * 8];
}

// ---------------- 128x128 MFMA GEMM, K=512: reg-staged + XCD swizzle + T14 + fused A-dtype ----
// A may be f32 (converted to bf16 during staging: 2x ld16 + cvt8) or bf16 per aflag
// (nullptr => bf16). Saves the standalone conv4(x) pass (~10-12 us).
template <bool BIAS>
__global__ __launch_bounds__(256) void gemm_k512(const void* __restrict__ A,
                                                 const u16* __restrict__ BT,
                                                 const u16* __restrict__ bias,
                                                 void* __restrict__ O, int ldo, int arow0,
                                                 int row0g, const u32* __restrict__ flag,
                                                 const u32* __restrict__ aflag) {
  constexpr int K = 512;
  constexpr int NT = 16;
  __shared__ u16 As[128 * 32];
  __shared__ u16 Bs[128 * 32];
  const bool isbfA = aflag ? (*aflag != 0u) : true;
  const int tid = threadIdx.x;
  const int wave = tid >> 6, lane = tid & 63;
  const int c = lane & 15, g = lane >> 4;
  const int wm = wave >> 1, wn = wave & 1;
  int bn, bm;
  swz_bn_bm(bn, bm);

  const size_t arow = (size_t)(arow0 + bm * 128);
  const u16* Bb = BT + (size_t)bn * 128 * K;

  const int row0 = tid >> 2, q0 = tid & 3;
  const u16* AsrcB0 = (const u16*)A + (arow + row0) * K + q0 * 8;
  const u16* AsrcB1 = AsrcB0 + (size_t)64 * K;
  const float* AsrcF0 = (const float*)A + (arow + row0) * K + q0 * 8;
  const float* AsrcF1 = AsrcF0 + (size_t)64 * K;
  const u16* Bsrc0 = Bb + (size_t)row0 * K + q0 * 8;
  const u16* Bsrc1 = Bsrc0 + (size_t)64 * K;

  f32x4 acc[4][4] = {};

  u32x4 a0lo, a0hi, a1lo, a1hi, b0, b1;
#define LOAD_AB(k0)                      \
  do {                                   \
    if (isbfA) {                         \
      a0lo = ld16(AsrcB0 + (k0));        \
      a1lo = ld16(AsrcB1 + (k0));        \
    } else {                             \
      a0lo = ld16f(AsrcF0 + (k0));       \
      a0hi = ld16f(AsrcF0 + (k0) + 4);   \
      a1lo = ld16f(AsrcF1 + (k0));       \
      a1hi = ld16f(AsrcF1 + (k0) + 4);   \
    }                                    \
    b0 = ld16(Bsrc0 + (k0));             \
    b1 = ld16(Bsrc1 + (k0));             \
  } while (0)

  LOAD_AB(0);

#pragma unroll
  for (int t = 0; t < NT; ++t) {
    if (t > 0) {
      asm volatile("s_waitcnt lgkmcnt(0)" ::: "memory");
      __builtin_amdgcn_s_barrier();
      __builtin_amdgcn_sched_barrier(0);
    }
    if (isbfA) {
      stage_fm(As, tid, a0lo);
      stage_fm(As, tid + 256, a1lo);
    } else {
      stage_fm(As, tid, cvt8(a0lo, a0hi));
      stage_fm(As, tid + 256, cvt8(a1lo, a1hi));
    }
    stage_fm(Bs, tid, b0);
    stage_fm(Bs, tid + 256, b1);
    if (t + 1 < NT) {  // T14: issue next-tile loads; they fly across barrier + MFMAs
      const int k0 = (t + 1) * 32;
      LOAD_AB(k0);
    }
    asm volatile("s_waitcnt lgkmcnt(0)" ::: "memory");
    __builtin_amdgcn_s_barrier();
    __builtin_amdgcn_sched_barrier(0);

    bf16x8 af[4], bfr[4];
#pragma unroll
    for (int i = 0; i < 4; ++i) {
      af[i] = frag_fm(As, wm * 4 + i, g, c);
      bfr[i] = frag_fm(Bs, wn * 4 + i, g, c);
    }
#pragma unroll
    for (int i = 0; i < 4; ++i)
#pragma unroll
      for (int j = 0; j < 4; ++j)
        acc[i][j] = __builtin_amdgcn_mfma_f32_16x16x32_bf16(af[i], bfr[j], acc[i][j], 0, 0, 0);
  }
#undef LOAD_AB

  const bool isbf = BIAS ? (*flag != 0u) : true;
#pragma unroll
  for (int i = 0; i < 4; ++i)
#pragma unroll
    for (int j = 0; j < 4; ++j) {
      int jg = bn * 128 + wn * 64 + j * 16 + c;
      float bv = BIAS ? bf2f(bias[jg]) : 0.0f;
#pragma unroll
      for (int r = 0; r < 4; ++r) {
        int mg = bm * 128 + wm * 64 + i * 16 + 4 * g + r;
        float v = acc[i][j][r] + bv;
        size_t off = (size_t)(row0g + mg) * ldo + jg;
        if (BIAS) {
          if (isbf) ((u16*)O)[off] = f2bf(v);
          else ((float*)O)[off] = v;
        } else {
          ((u16*)O)[off] = f2bf(v);
        }
      }
    }
}

// ---------------- fused attention (r15 version, measured 49.7us): K+V staged, 2 rg/wave ------
__global__ __launch_bounds__(256) void attn_kernel(const u16* __restrict__ qkv,
                                                   const float* __restrict__ biasT,
                                                   u16* __restrict__ Out) {
  __shared__ u16 smem[18432];
  float* biasS = (float*)&smem[16384];

  const int tid = threadIdx.x;
  const int wave = tid >> 6, lane = tid & 63;
  const int c = lane & 15, g = lane >> 4;
  const int half = blockIdx.x & 1;
  const int h = (blockIdx.x >> 1) & 15;
  const int b = blockIdx.x >> 5;

  const u16* xb = qkv + (size_t)b * 256 * 1536;

  // stage K (256 rows x 32 dims) fragment-major (register path)
  u32x4 kvr[4];
#pragma unroll
  for (int i = 0; i < 4; ++i) {
    int ch = tid + i * 256;
    int m = ch >> 2;
    kvr[i] = ld16(xb + (size_t)m * 1536 + 512 + h * 32 + (ch & 3) * 8);
  }
#pragma unroll
  for (int i = 0; i < 4; ++i) stage_fm(smem, tid + i * 256, kvr[i]);

  // stage V transposed + swizzled: element (n,d) -> Vt[d][n ^ 8*(d&7)]
#pragma unroll
  for (int i = 0; i < 16; ++i) {
    int e2 = tid + i * 256;
    int n = e2 >> 4, d = (e2 & 15) * 2;
    u32 val = *(const u32*)(xb + (size_t)n * 1536 + 1024 + h * 32 + d);
    smem[8192 + d * 256 + (n ^ (8 * (d & 7)))] = (u16)(val & 0xffffu);
    smem[8192 + (d + 1) * 256 + (n ^ (8 * ((d + 1) & 7)))] = (u16)(val >> 16);
  }
  // bias: coalesced f32 row for this head (already *log2e)
  for (int i = tid; i < 961; i += 256) biasS[i] = biasT[h * 961 + i];

  // hoist this block's 2 row-groups of Q (contiguous k-map: one 16B load each)
  u32x4 qv[2];
#pragma unroll
  for (int rg = 0; rg < 2; ++rg) {
    const u16* qp = xb + (size_t)((half * 2 + rg) * 64 + wave * 16 + c) * 1536 + h * 32 + 8 * g;
    qv[rg] = ld16(qp);
  }
  __syncthreads();  // only barrier

  const u16* Vt = &smem[8192];
  const int va = 8 * (c & 7);
  const float scale2 = 0.25503484f;  // log2(e) / sqrt(32)
  const float* bp0 = biasS + wave * 31 + c + 12 - 4 * g;

#pragma unroll
  for (int rg = 0; rg < 2; ++rg) {
    const int rgg = half * 2 + rg;
    union { bf16x8 v; u32x4 u; } qt;
    qt.u = qv[rg];
    bf16x8 qf = qt.v;

    f32x4 o0 = {0.f, 0.f, 0.f, 0.f}, o1 = {0.f, 0.f, 0.f, 0.f};
    float smm = 0.f;

#pragma unroll
    for (int ph = 0; ph < 2; ++ph) {
      f32x4 s[8];
#pragma unroll
      for (int f = 0; f < 8; ++f) {
        bf16x8 kf = frag_fm(smem, ph * 8 + f, g, c);
        f32x4 z = {0.f, 0.f, 0.f, 0.f};
        s[f] = __builtin_amdgcn_mfma_f32_16x16x32_bf16(kf, qf, z, 0, 0, 0);
      }

      float u[8];
#pragma unroll
      for (int f = 0; f < 8; ++f) {
        const int fg = ph * 8 + f;
#pragma unroll
        for (int j = 0; j < 4; ++j) {
          float bv = bp0[(rgg * 4 - fg + 15) * 31 + 3 - j];
          s[f][j] = __builtin_amdgcn_exp2f(s[f][j] * scale2 + bv);
        }
        u[f] = (s[f][0] + s[f][1]) + (s[f][2] + s[f][3]);
      }
      smm += ((u[0] + u[4]) + (u[1] + u[5])) + ((u[2] + u[6]) + (u[3] + u[7]));

#pragma unroll
      for (int q = 0; q < 4; ++q) {
        bf16x8 pf;
        pf[0] = (__bf16)s[2 * q][0]; pf[1] = (__bf16)s[2 * q][1];
        pf[2] = (__bf16)s[2 * q][2]; pf[3] = (__bf16)s[2 * q][3];
        pf[4] = (__bf16)s[2 * q + 1][0]; pf[5] = (__bf16)s[2 * q + 1][1];
        pf[6] = (__bf16)s[2 * q + 1][2]; pf[7] = (__bf16)s[2 * q + 1][3];
        const int kg = (ph * 4 + q) * 32;
        bf16x8 v0 = mk_frag(ld8(&Vt[c * 256 + ((kg + 4 * g) ^ va)]),
                            ld8(&Vt[c * 256 + ((kg + 16 + 4 * g) ^ va)]));
        bf16x8 v1 = mk_frag(ld8(&Vt[(16 + c) * 256 + ((kg + 4 * g) ^ va)]),
                            ld8(&Vt[(16 + c) * 256 + ((kg + 16 + 4 * g) ^ va)]));
        o0 = __builtin_amdgcn_mfma_f32_16x16x32_bf16(pf, v0, o0, 0, 0, 0);
        o1 = __builtin_amdgcn_mfma_f32_16x16x32_bf16(pf, v1, o1, 0, 0, 0);
      }
    }

    smm += __shfl_xor(smm, 16, 64);
    smm += __shfl_xor(smm, 32, 64);
    const float invc = __builtin_amdgcn_rcpf(smm);

    const int nb = rgg * 64 + wave * 16 + 4 * g;
#pragma unroll
    for (int j = 0; j < 4; ++j) {
      int n = nb + j;
      size_t off = ((size_t)b * 256 + n) * 512 + h * 32;
      Out[off + c] = cvbf(o0[j] * invc);
      Out[off + 16 + c] = cvbf(o1[j] * invc);
    }
  }
}

extern "C" void kernel_launch(void* const* d_in, const int* in_sizes, int n_in, void* d_out,
                              int out_size, void* d_ws, size_t ws_size, hipStream_t stream) {
  (void)in_sizes; (void)n_in; (void)out_size;
  const void* x = d_in[0];
  const void* w_qkv = d_in[1];
  const void* table = d_in[2];
  const void* w_out = d_in[3];
  const void* b_out = d_in[4];

  // Workspace layout (bytes): x is no longer copied (conversion fused into gemm1's A-staging)
  //   0        flag (u32, 256B reserved)
  //   256      wqkvT  bf16 [1536][512]     1,572,864
  //   1573120  biasT  f32  [16][961]          61,504
  //   1634624  woC    bf16 [512][512]        524,288
  //   2158912  bC     bf16 [512]               1,024
  //   2160128  qkv chunk bf16 [CB*256][1536] + att chunk bf16 [CB*256][512]
  char* ws = (char*)d_ws;
  u32* flag = (u32*)ws;
  u16* wqkvT = (u16*)(ws + 256);
  float* biasT = (float*)(ws + 1573120);
  u16* woC = (u16*)(ws + 1634624);
  u16* bC = (u16*)(ws + 2158912);
  const size_t DYN = 2160128;
  int CB = 64;
  while (CB > 1 && DYN + (size_t)CB * 1048576 > ws_size) CB >>= 1;
  u16* qkv = (u16*)(ws + DYN);
  u16* att = (u16*)(ws + DYN + (size_t)CB * 786432);

  dim3 blk(256);
  probe_dtype<<<dim3(1), dim3(64), 0, stream>>>((const u32*)x, flag);
  conv4<<<dim3(256), blk, 0, stream>>>(w_out, woC, flag, 65536);
  conv4<<<dim3(1), blk, 0, stream>>>(b_out, bC, flag, 128);
  bias_prep<<<dim3(61), blk, 0, stream>>>(table, biasT, flag);
  transpose_dt<<<dim3(48, 16), blk, 0, stream>>>(w_qkv, wqkvT, flag, 512, 1536);

  for (int s0 = 0; s0 < 64; s0 += CB) {
    gemm_k512<false><<<dim3(12, CB * 2), blk, 0, stream>>>(x, wqkvT, nullptr, qkv, 1536,
                                                           s0 * 256, 0, flag, flag);
    attn_kernel<<<dim3(CB * 32), blk, 0, stream>>>(qkv, biasT, att);
    gemm_k512<true><<<dim3(4, CB * 2), blk, 0, stream>>>(att, woC, bC, d_out, 512, 0, s0 * 256,
                                                         flag, nullptr);
  }
}